// Round 3
// baseline (618.451 us; speedup 1.0000x reference)
//
#include <hip/hip_runtime.h>
#include <stdint.h>

// ---------------------------------------------------------------------------
// MLA attention, MI355X gfx950.
// Shapes: B=2 S=2048 D=2048 H=16 HD=128 ND=64 RD=64 R=512
// ABI (established rounds 1-2): all 7 inputs fp32, output fp32.
// Internal compute: bf16 intermediates, fp32 MFMA accumulation.
// ---------------------------------------------------------------------------

typedef unsigned short u16;
typedef __bf16 bf16x8 __attribute__((ext_vector_type(8)));
typedef float f32x4 __attribute__((ext_vector_type(4)));

__device__ __forceinline__ float bf2f(u16 u) {
    union { unsigned int i; float f; } x; x.i = ((unsigned int)u) << 16; return x.f;
}
__device__ __forceinline__ u16 f2bf(float f) {
    union { float f; unsigned int i; } x; x.f = f;
    unsigned int r = x.i + 0x7fffu + ((x.i >> 16) & 1u);   // RNE, finite inputs only
    return (u16)(r >> 16);
}
__device__ __forceinline__ void store_c(u16* p, float v)  { *p = f2bf(v); }
__device__ __forceinline__ void store_c(float* p, float v){ *p = v; }

#define GLOBAL_AS __attribute__((address_space(1)))
#define LDS_AS    __attribute__((address_space(3)))
// async global->LDS, 16B per lane. LDS dest must be wave-uniform base + lane*16.
__device__ __forceinline__ void gl_lds16(const void* g, void* l) {
    __builtin_amdgcn_global_load_lds((GLOBAL_AS const void*)g, (LDS_AS void*)l, 16, 0, 0);
}

// ---------------------------------------------------------------------------
// fp32 -> bf16 conversion, 8 elements/thread.
// ---------------------------------------------------------------------------
__global__ void convert_in(const float* __restrict__ src, u16* __restrict__ dst,
                           int n8) {
    int i = blockIdx.x * 256 + threadIdx.x;
    if (i >= n8) return;
    const float4* s = (const float4*)src;
    float4 v0 = s[2*i], v1 = s[2*i + 1];
    union { u16 u[8]; uint4 v; } o;
    o.u[0] = f2bf(v0.x); o.u[1] = f2bf(v0.y); o.u[2] = f2bf(v0.z); o.u[3] = f2bf(v0.w);
    o.u[4] = f2bf(v1.x); o.u[5] = f2bf(v1.y); o.u[6] = f2bf(v1.z); o.u[7] = f2bf(v1.w);
    *((uint4*)(dst + 8*i)) = o.v;
}

// ---------------------------------------------------------------------------
// GEMM: C[m][n] = sum_k A[m][k] * W[n][k]   (A: MxK, W: NxK, row-major, bf16)
// m97-style: BK=32, wave = 64x64 via 4x4 grid of 16x16x32 MFMA,
// global_load_lds width-16 staging. M%BM==0, N%BN==0, K%32==0 assumed.
// CT = u16 (bf16 store) or float (fp32 store).
// ---------------------------------------------------------------------------
template<int BM, int BN, typename CT>
__global__ __launch_bounds__((BM/64)*(BN/64)*64)
void gemm_bt(const u16* __restrict__ A, const u16* __restrict__ W,
             CT* __restrict__ C, int M, int N, int K) {
    constexpr int BK = 32;
    constexpr int NWAVE = (BM/64)*(BN/64);
    constexpr int NT = NWAVE * 64;
    __shared__ u16 As[BM*BK];
    __shared__ u16 Bs[BN*BK];
    const int tid  = threadIdx.x;
    const int lane = tid & 63, l15 = lane & 15, quad = lane >> 4;
    const int wave = tid >> 6;
    const int wm = wave % (BM/64);
    const int wn = wave / (BM/64);
    const int bm = blockIdx.y * BM;
    const int bn = blockIdx.x * BN;

    const f32x4 fzero = {0.f, 0.f, 0.f, 0.f};
    f32x4 acc[4][4];
    #pragma unroll
    for (int i = 0; i < 4; ++i)
        #pragma unroll
        for (int j = 0; j < 4; ++j) acc[i][j] = fzero;

    const size_t Kb = (size_t)K * 2;   // row stride in bytes

    for (int k0 = 0; k0 < K; k0 += BK) {
        #pragma unroll
        for (int i = 0; i < (BM*64)/(NT*16); ++i) {
            int o = (tid + i*NT) * 16;
            int row = o >> 6, colb = o & 63;
            gl_lds16((const char*)A + (size_t)(bm + row)*Kb + (size_t)k0*2 + colb,
                     (char*)As + o);
        }
        #pragma unroll
        for (int i = 0; i < (BN*64)/(NT*16); ++i) {
            int o = (tid + i*NT) * 16;
            int row = o >> 6, colb = o & 63;
            gl_lds16((const char*)W + (size_t)(bn + row)*Kb + (size_t)k0*2 + colb,
                     (char*)Bs + o);
        }
        __syncthreads();

        bf16x8 af[4], bfv[4];
        #pragma unroll
        for (int mt = 0; mt < 4; ++mt)
            af[mt] = *reinterpret_cast<const bf16x8*>(&As[(wm*64 + mt*16 + l15)*BK + quad*8]);
        #pragma unroll
        for (int nt = 0; nt < 4; ++nt)
            bfv[nt] = *reinterpret_cast<const bf16x8*>(&Bs[(wn*64 + nt*16 + l15)*BK + quad*8]);
        #pragma unroll
        for (int mt = 0; mt < 4; ++mt)
            #pragma unroll
            for (int nt = 0; nt < 4; ++nt)
                acc[mt][nt] = __builtin_amdgcn_mfma_f32_16x16x32_bf16(
                    af[mt], bfv[nt], acc[mt][nt], 0, 0, 0);
        __syncthreads();
    }

    // epilogue: C/D layout col=lane&15, row=quad*4+reg (m89/m91 verified)
    #pragma unroll
    for (int mt = 0; mt < 4; ++mt)
        #pragma unroll
        for (int nt = 0; nt < 4; ++nt)
            #pragma unroll
            for (int r = 0; r < 4; ++r) {
                int gm = bm + wm*64 + mt*16 + quad*4 + r;
                int gn = bn + wn*64 + nt*16 + l15;
                store_c(&C[(size_t)gm * N + gn], acc[mt][nt][r]);
            }
}

// ---------------------------------------------------------------------------
// In-place RoPE on bf16 buffer. One thread per (row, pair i of 32).
// pos = (row / pos_div) % 2048.  out[2i]   = x[2i]*cos - x[2i+1]*sin
//                                out[2i+1] = x[2i+1]*cos + x[2i]*sin
// ---------------------------------------------------------------------------
__global__ void rope_kernel(u16* buf, int total_pairs, int row_stride,
                            int col_off, int pos_div) {
    int idx = blockIdx.x * 256 + threadIdx.x;
    if (idx >= total_pairs) return;
    int row = idx >> 5;
    int i   = idx & 31;
    int pos = (row / pos_div) & 2047;                // % S
    float freq = powf(10000.0f, -(float)i * (1.0f/32.0f));  // theta^(-2i/64)
    float ang  = (float)pos * freq;
    float s = sinf(ang), c = cosf(ang);              // accurate range reduction
    u16* p = buf + (size_t)row * row_stride + col_off + 2*i;
    float x0 = bf2f(p[0]), x1 = bf2f(p[1]);
    p[0] = f2bf(x0*c - x1*s);
    p[1] = f2bf(x1*c + x0*s);
}

// ---------------------------------------------------------------------------
// Flash-style causal attention.
// grid = (S/64 q-tiles, B*H). block = 256 (4 waves). Wave w owns q-rows
// w*16..w*16+15 of the 64-row Q tile. K_eff = [k_nope(64) | k_rope(64)].
// Ks LDS is column-chunk XOR-swizzled (chunk c stored at c ^ (row&15)) so
// QK^T B-frag b128 reads are ~2-way instead of 16-way conflicted; the swizzle
// is applied on the GLOBAL source address (global_load_lds forces linear LDS).
// ---------------------------------------------------------------------------
__global__ __launch_bounds__(256)
void attn_kernel(const u16* __restrict__ Q, const u16* __restrict__ KN,
                 const u16* __restrict__ KR, const u16* __restrict__ V,
                 u16* __restrict__ Oout) {
    constexpr int S = 2048;
    const int qt = blockIdx.x;
    const int bh = blockIdx.y;
    const int b = bh >> 4, h = bh & 15;

    __shared__ u16 Qs[64*128];     // natural layout
    __shared__ u16 Ks[64*128];     // swizzled chunks
    __shared__ u16 Vs[64*128];     // natural layout
    __shared__ u16 Ps[4*16*72];    // per-wave P, row stride 72 (pad for banks)

    const int tid  = threadIdx.x;
    const int lane = tid & 63, l15 = lane & 15, quad = lane >> 4;
    const int wave = tid >> 6;

    // stage Q tile (64 x 128), once
    const u16* qbase = Q + ((size_t)(b*S + qt*64) * 2048 + h*128);
    #pragma unroll
    for (int i = 0; i < 4; ++i) {
        int o = (tid + i*256) * 16;
        int row = o >> 8, colb = o & 255;
        gl_lds16((const char*)qbase + (size_t)row*4096 + colb, (char*)Qs + o);
    }
    __syncthreads();
    // Q A-frags, loop-invariant: A[m=lane&15][k=quad*8+j], 4 k-steps of 32
    bf16x8 aq[4];
    #pragma unroll
    for (int ks = 0; ks < 4; ++ks)
        aq[ks] = *reinterpret_cast<const bf16x8*>(&Qs[(wave*16 + l15)*128 + ks*32 + quad*8]);

    const f32x4 fzero = {0.f, 0.f, 0.f, 0.f};
    const float NEG = -1e30f;      // mask sentinel: no overflow corner, exp -> 0
    float m_i[4] = {NEG, NEG, NEG, NEG};
    float l_i[4] = {0.f, 0.f, 0.f, 0.f};
    f32x4 oacc[8];
    #pragma unroll
    for (int i = 0; i < 8; ++i) oacc[i] = fzero;

    const float scale = 0.08838834764831845f;   // 1/sqrt(128)
    const int qrow0 = qt*64 + wave*16 + quad*4;

    for (int kt = 0; kt <= qt; ++kt) {
        const char* knb = (const char*)(KN + ((size_t)(b*S + kt*64)*1024 + h*64));
        const char* krb = (const char*)(KR + ((size_t)(b*S + kt*64)*64));
        const char* vbp = (const char*)(V  + ((size_t)(b*S + kt*64)*2048 + h*128));
        #pragma unroll
        for (int i = 0; i < 4; ++i) {
            int o = (tid + i*256) * 16;
            int row   = o >> 8;
            int c_lds = (o >> 4) & 15;
            int cg    = c_lds ^ (row & 15);     // logical 16B chunk for this slot
            const char* g = (cg < 8) ? (knb + (size_t)row*2048 + cg*16)
                                     : (krb + (size_t)row*128 + (cg - 8)*16);
            gl_lds16(g, (char*)Ks + o);
            gl_lds16(vbp + (size_t)row*4096 + (o & 255), (char*)Vs + o);
        }
        __syncthreads();

        // S = Q K^T (per wave: 16 q-rows x 64 kv-cols)
        f32x4 sfr[4];
        #pragma unroll
        for (int nt = 0; nt < 4; ++nt) {
            f32x4 s = fzero;
            int n = nt*16 + l15;
            #pragma unroll
            for (int ks = 0; ks < 4; ++ks) {
                int c = ks*4 + quad;            // logical chunk along k
                bf16x8 bk = *reinterpret_cast<const bf16x8*>(&Ks[n*128 + ((c ^ l15) * 8)]);
                s = __builtin_amdgcn_mfma_f32_16x16x32_bf16(aq[ks], bk, s, 0, 0, 0);
            }
            sfr[nt] = s;
        }
        // scale + causal mask
        #pragma unroll
        for (int nt = 0; nt < 4; ++nt) {
            int kg = kt*64 + nt*16 + l15;
            #pragma unroll
            for (int r = 0; r < 4; ++r) {
                float v = sfr[nt][r] * scale;
                sfr[nt][r] = (kg <= qrow0 + r) ? v : NEG;
            }
        }
        // online softmax (rows live across the quad's 16 lanes)
        float rm[4];
        #pragma unroll
        for (int r = 0; r < 4; ++r)
            rm[r] = fmaxf(fmaxf(sfr[0][r], sfr[1][r]), fmaxf(sfr[2][r], sfr[3][r]));
        #pragma unroll
        for (int off = 1; off < 16; off <<= 1)
            #pragma unroll
            for (int r = 0; r < 4; ++r)
                rm[r] = fmaxf(rm[r], __shfl_xor(rm[r], off, 64));

        float alpha[4];
        #pragma unroll
        for (int r = 0; r < 4; ++r) {
            float mn = fmaxf(m_i[r], rm[r]);
            alpha[r] = __expf(m_i[r] - mn);     // first tile: exp(-1e30) = 0
            m_i[r] = mn;
            l_i[r] *= alpha[r];
        }
        float rs[4] = {0.f, 0.f, 0.f, 0.f};
        float pf[4][4];
        #pragma unroll
        for (int nt = 0; nt < 4; ++nt)
            #pragma unroll
            for (int r = 0; r < 4; ++r) {
                float p = __expf(sfr[nt][r] - m_i[r]);
                pf[nt][r] = p;
                rs[r] += p;
            }
        #pragma unroll
        for (int off = 1; off < 16; off <<= 1)
            #pragma unroll
            for (int r = 0; r < 4; ++r)
                rs[r] += __shfl_xor(rs[r], off, 64);
        #pragma unroll
        for (int r = 0; r < 4; ++r) l_i[r] += rs[r];
        #pragma unroll
        for (int i = 0; i < 8; ++i)
            #pragma unroll
            for (int r = 0; r < 4; ++r)
                oacc[i][r] *= alpha[r];

        // P: C-layout -> LDS -> A-layout (wave-private region, no barrier)
        #pragma unroll
        for (int nt = 0; nt < 4; ++nt)
            #pragma unroll
            for (int r = 0; r < 4; ++r)
                Ps[(wave*16 + quad*4 + r)*72 + nt*16 + l15] = f2bf(pf[nt][r]);

        // O += P V : A = P (16x64), B-frag = V^T via scalar LDS reads
        #pragma unroll
        for (int ks = 0; ks < 2; ++ks) {
            bf16x8 pa = *reinterpret_cast<const bf16x8*>(&Ps[(wave*16 + l15)*72 + ks*32 + quad*8]);
            #pragma unroll
            for (int ntv = 0; ntv < 8; ++ntv) {
                union { bf16x8 v; u16 u[8]; } bv;
                #pragma unroll
                for (int j = 0; j < 8; ++j)
                    bv.u[j] = Vs[(ks*32 + quad*8 + j)*128 + ntv*16 + l15];
                oacc[ntv] = __builtin_amdgcn_mfma_f32_16x16x32_bf16(pa, bv.v, oacc[ntv], 0, 0, 0);
            }
        }
        __syncthreads();   // before next tile overwrites Ks/Vs
    }

    // epilogue: normalize and write (b, s, h*128+d)
    u16* obase = Oout + ((size_t)(b*S + qt*64) * 2048 + h*128);
    #pragma unroll
    for (int r = 0; r < 4; ++r) {
        float inv = 1.0f / l_i[r];
        int qrow = wave*16 + quad*4 + r;
        #pragma unroll
        for (int ntv = 0; ntv < 8; ++ntv) {
            int d = ntv*16 + l15;
            obase[(size_t)qrow*2048 + d] = f2bf(oacc[ntv][r] * inv);
        }
    }
}

// ---------------------------------------------------------------------------
// Host launcher. Inputs fp32, output fp32.
// ---------------------------------------------------------------------------
extern "C" void kernel_launch(void* const* d_in, const int* in_sizes, int n_in,
                              void* d_out, int out_size, void* d_ws, size_t ws_size,
                              hipStream_t stream) {
    (void)in_sizes; (void)n_in; (void)out_size; (void)ws_size;
    float* out = (float*)d_out;
    char* ws = (char*)d_ws;

    // workspace layout (bytes) — total ~77.3 MB
    u16* q      = (u16*)(ws);                  // 4096x2048 = 16,777,216 B
    u16* ckv    = (u16*)(ws + 16777216);       // 4096x512     4,194,304 B
    u16* kr     = (u16*)(ws + 20971520);       // 4096x64        524,288 B
    u16* v      = (u16*)(ws + 21495808);       // 4096x2048   16,777,216 B
    u16* xc     = (u16*)(ws + 38273024);       // 4096x2048   16,777,216 B (attn reuses)
    u16* wqc    = (u16*)(ws + 55050240);       // 1024x2048    8,388,608 B (kn reuses)
    u16* kvdc   = (u16*)(ws + 63438848);       // 512x2048     2,097,152 B
    u16* kupc   = (u16*)(ws + 65536000);       // 1024x512     1,048,576 B
    u16* kropec = (u16*)(ws + 66584576);       // 64x2048        262,144 B
    u16* vupc   = (u16*)(ws + 66846720);       // 2048x512     2,097,152 B
    u16* woc    = (u16*)(ws + 68943872);       // 2048x2048    8,388,608 B
    u16* attn   = xc;    // xc dead after the 3 projections
    u16* kn     = wqc;   // wqc dead after q gemm

    // 1) canonicalize all fp32 inputs to bf16 workspace copies
    struct { const void* src; u16* dst; int n; } conv[7] = {
        { d_in[0], xc,     4096*2048 },
        { d_in[1], wqc,    2048*2048 },
        { d_in[2], kvdc,    512*2048 },
        { d_in[3], kupc,   1024*512  },
        { d_in[4], kropec,   64*2048 },
        { d_in[5], vupc,   2048*512  },
        { d_in[6], woc,    2048*2048 },
    };
    for (int i = 0; i < 7; ++i) {
        int n8 = conv[i].n / 8;
        convert_in<<<(n8 + 255)/256, 256, 0, stream>>>((const float*)conv[i].src,
                                                       conv[i].dst, n8);
    }

    // 2) projections (bf16 out)
    gemm_bt<128,128><<<dim3(16, 32), 256, 0, stream>>>(xc, wqc, q, 4096, 2048, 2048);
    gemm_bt<128,128><<<dim3(4, 32), 256, 0, stream>>>(xc, kvdc, ckv, 4096, 512, 2048);
    gemm_bt<128,64><<<dim3(1, 32), 128, 0, stream>>>(xc, kropec, kr, 4096, 64, 2048);

    // 3) RoPE: q rope-half (rows=(b*S+s)*16+h, stride 128, cols 64..127); kr full
    rope_kernel<<<(2097152 + 255)/256, 256, 0, stream>>>(q, 2097152, 128, 64, 16);
    rope_kernel<<<(131072 + 255)/256, 256, 0, stream>>>(kr, 131072, 64, 0, 1);

    // 4) up-projections
    gemm_bt<128,128><<<dim3(8, 32), 256, 0, stream>>>(ckv, kupc, kn, 4096, 1024, 512);
    gemm_bt<128,128><<<dim3(16, 32), 256, 0, stream>>>(ckv, vupc, v, 4096, 2048, 512);

    // 5) attention: grid (q-tiles, b*h)
    attn_kernel<<<dim3(32, 32), 256, 0, stream>>>(q, kn, kr, v, attn);

    // 6) output projection -> fp32 directly into d_out
    gemm_bt<128,128><<<dim3(16, 32), 256, 0, stream>>>(attn, woc, out, 4096, 2048, 2048);
}